// Round 8
// baseline (71.740 us; speedup 1.0000x reference)
//
#include <hip/hip_runtime.h>
#include <hip/hip_bf16.h>

// Problem constants
#define TT 2048
#define BB 4
#define CC 512
#define HH 16
#define KK 31
#define PP 15
#define MM (TT*BB)      // 8192 rows
#define NPAD 512        // HK=496 padded to 512 (pad rows of Wl are zero)

typedef __bf16 bf16x8 __attribute__((ext_vector_type(8)));
typedef float f32x4 __attribute__((ext_vector_type(4)));
typedef unsigned short ushort8 __attribute__((ext_vector_type(8)));
typedef unsigned short ushort4v __attribute__((ext_vector_type(4)));

__device__ __forceinline__ float bf2f(unsigned short u) {
    return __uint_as_float(((unsigned int)u) << 16);
}
__device__ __forceinline__ unsigned short f2bf(float f) {
    unsigned int x = __float_as_uint(f);
    x += 0x7fffu + ((x >> 16) & 1u);
    return (unsigned short)(x >> 16);
}

// ---------------------------------------------------------------------------
// cast fp32 -> bf16 for x (4 elems/thread)
// ---------------------------------------------------------------------------
__global__ __launch_bounds__(256) void cast_x(const float* __restrict__ src,
                                              unsigned short* __restrict__ dst) {
    const int i = (blockIdx.x * 256 + threadIdx.x) * 4;
    const float4 v = *(const float4*)&src[i];
    ushort4v o = { f2bf(v.x), f2bf(v.y), f2bf(v.z), f2bf(v.w) };
    *(ushort4v*)&dst[i] = o;
}

// ---------------------------------------------------------------------------
// cast all three weight matrices in one dispatch (768 blocks x 1024 elems).
// Wl rows 496..511 are zero-padded.
// ---------------------------------------------------------------------------
__global__ __launch_bounds__(256) void cast_weights(const float* __restrict__ W1,
                                                    const float* __restrict__ Wl,
                                                    const float* __restrict__ W2,
                                                    unsigned short* __restrict__ W1b,
                                                    unsigned short* __restrict__ Wlb,
                                                    unsigned short* __restrict__ W2b) {
    const int b = blockIdx.x;
    const int i = (b & 255) * 1024 + threadIdx.x * 4;
    const float* src;
    unsigned short* dst;
    int n_src = 262144;
    if (b < 256)      { src = W1; dst = W1b; }
    else if (b < 512) { src = Wl; dst = Wlb; n_src = HH * KK * CC; }
    else              { src = W2; dst = W2b; }
    ushort4v o = {0, 0, 0, 0};
    if (i < n_src) {
        const float4 v = *(const float4*)&src[i];
        o[0] = f2bf(v.x); o[1] = f2bf(v.y); o[2] = f2bf(v.z); o[3] = f2bf(v.w);
    }
    *(ushort4v*)&dst[i] = o;
}

// ---------------------------------------------------------------------------
// bf16 MFMA GEMM-NT, 3-stage A-pipeline + B-from-global-regs:
// C[m,n] = sum_k A[m,k]*B[n,k] (+bias[n]); K=512 (NT=8 x BK=64).
// 128x64 tile, 256 thr = 4 waves (2x2), each wave 64x32 out.
// A: global_load_lds into 3-stage LDS (counted vmcnt, never 0 in-loop).
// B: L2-resident (0.5 MB panel, XCD swizzle) -> direct global->reg loads,
//    double-buffered one K-tile ahead; compiler tracks the reg dependency.
// Per iter kt: {loadB(kt+1); vmcnt(8); s_barrier; stageA(kt+2); compute(kt)}.
// vmcnt(8) retires the oldest 8 = A(kt)+B(kt): exactly what compute needs.
// LDS 3x16=48 KB. 512 blocks -> 2 blocks/CU. Swizzle slot^=(row&7).
// ---------------------------------------------------------------------------
#define GBM 128
#define GBN 64
#define GBK 64
#define KC  512
#define NT  8

#define STAGE(kt, buf)                                                                         \
    do {                                                                                       \
        const int k0_ = (kt) * GBK;                                                            \
        _Pragma("unroll")                                                                      \
        for (int j = 0; j < 4; ++j)                                                            \
            __builtin_amdgcn_global_load_lds(                                                  \
                (const __attribute__((address_space(1))) void*)(gA[j] + k0_),                  \
                (__attribute__((address_space(3))) void*)(&As[buf][0] + j * 2048 + wv * 512),  \
                16, 0, 0);                                                                     \
    } while (0)

#define LOADB(kt, pb)                                                                          \
    do {                                                                                       \
        _Pragma("unroll")                                                                      \
        for (int ni = 0; ni < 2; ++ni)                                                         \
            _Pragma("unroll")                                                                  \
            for (int ks = 0; ks < 2; ++ks)                                                     \
                pb[ni][ks] = *(const bf16x8*)(gBreg[ni] + (kt) * GBK + ks * 32);               \
    } while (0)

#define COMPUTE(pb)                                                                            \
    do {                                                                                       \
        bf16x8 af[4][2];                                                                       \
        _Pragma("unroll")                                                                      \
        for (int mi = 0; mi < 4; ++mi)                                                         \
            _Pragma("unroll")                                                                  \
            for (int ks = 0; ks < 2; ++ks)                                                     \
                af[mi][ks] = *(const bf16x8*)&As[cb][offA[mi][ks]];                            \
        _Pragma("unroll")                                                                      \
        for (int mi = 0; mi < 4; ++mi)                                                         \
            _Pragma("unroll")                                                                  \
            for (int ni = 0; ni < 2; ++ni)                                                     \
                _Pragma("unroll")                                                              \
                for (int ks = 0; ks < 2; ++ks)                                                 \
                    acc[mi][ni] = __builtin_amdgcn_mfma_f32_16x16x32_bf16(af[mi][ks],          \
                                      pb[ni][ks], acc[mi][ni], 0, 0, 0);                       \
    } while (0)

template<bool OUT_BF16>
__global__ __launch_bounds__(256, 2) void gemm_nt_mfma(const unsigned short* __restrict__ A,
                                                       const unsigned short* __restrict__ B,
                                                       const float* __restrict__ bias,
                                                       void* __restrict__ Cout,
                                                       int N, int nn) {
    __shared__ short As[3][GBM * GBK];   // 3 x 16 KB

    const int tid = threadIdx.x;
    const int l   = tid & 63;
    const int wv  = tid >> 6;      // wave 0..3
    const int wr  = wv >> 1;       // wave row (0..1) -> 64 rows
    const int wc  = wv & 1;        // wave col (0..1) -> 32 cols

    // chunked XCD swizzle; consecutive s share A panel + whole B in XCD L2
    const int s  = (blockIdx.x & 7) * (gridDim.x >> 3) + (blockIdx.x >> 3);
    const int bm = (s / nn) * GBM;
    const int bn = (s % nn) * GBN;

    // A staging: 128 rows x 8 slots(16B) = 4 rounds x 256 thr. Linear LDS
    // dest; source slot pre-swizzled slot' = slot ^ (row&7) (involution).
    const unsigned short* gA[4];
    #pragma unroll
    for (int j = 0; j < 4; ++j) {
        const int idx16 = j * 256 + tid;
        const int r  = idx16 >> 3;
        const int sl = (idx16 & 7) ^ (r & 7);
        gA[j] = A + (size_t)(bm + r) * KC + sl * 8;
    }

    const int lr = l & 15;     // fragment row-within-16
    const int ls = l >> 4;     // k-slot (8 bf16 each)

    // B fragment base pointers (per lane): row = C-col, 16B at k-offset
    const unsigned short* gBreg[2];
    #pragma unroll
    for (int ni = 0; ni < 2; ++ni)
        gBreg[ni] = B + (size_t)(bn + wc * 32 + ni * 16 + lr) * KC + ls * 8;

    f32x4 acc[4][2] = {};

    int offA[4][2];
    #pragma unroll
    for (int mi = 0; mi < 4; ++mi) {
        const int r = wr * 64 + mi * 16 + lr;
        #pragma unroll
        for (int ks = 0; ks < 2; ++ks)
            offA[mi][ks] = r * 64 + (((ks * 4 + ls) ^ (r & 7)) * 8);
    }

    bf16x8 bq0[2][2], bq1[2][2];

    // prologue: A(0), B(0), A(1)  (order matters for the vmcnt counts)
    STAGE(0, 0);
    LOADB(0, bq0);
    STAGE(1, 1);

    #pragma unroll
    for (int kt = 0; kt < NT; ++kt) {
        // (a) prefetch next B tile into the other reg buffer
        if (kt + 1 < NT) {
            if (kt & 1) LOADB(kt + 1, bq0);
            else        LOADB(kt + 1, bq1);
        }
        // (b) retire oldest 8 VMEM ops = A(kt) stage + B(kt) regs
        if (kt < NT - 1) asm volatile("s_waitcnt vmcnt(8)" ::: "memory");
        else             asm volatile("s_waitcnt vmcnt(0)" ::: "memory");
        __builtin_amdgcn_s_barrier();
        // (c) prefetch A tile kt+2 (overwrites buf[(kt-1)%3], safe post-barrier)
        if (kt + 2 < NT) STAGE(kt + 2, (kt + 2) % 3);

        // (d) compute on A-buf kt%3 with B regs kt&1
        const int cb = kt % 3;
        if (kt & 1) COMPUTE(bq1);
        else        COMPUTE(bq0);
    }

    // C/D layout (m89): col = lane&15, row = (lane>>4)*4 + j
    #pragma unroll
    for (int mi = 0; mi < 4; ++mi) {
        const int row0 = bm + wr * 64 + mi * 16 + ls * 4;
        #pragma unroll
        for (int ni = 0; ni < 2; ++ni) {
            const int col = bn + wc * 32 + ni * 16 + lr;
            const float bv = bias ? bias[col] : 0.0f;
            #pragma unroll
            for (int j = 0; j < 4; ++j) {
                const float v = acc[mi][ni][j] + bv;
                if (OUT_BF16)
                    ((unsigned short*)Cout)[(size_t)(row0 + j) * N + col] = f2bf(v);
                else
                    ((float*)Cout)[(size_t)(row0 + j) * N + col] = v;
            }
        }
    }
}

// ---------------------------------------------------------------------------
// Fused softmax + rolling dynamic conv.
// Block = (4 consecutive t, one b), 64 threads (1 wave).
// Phase 1: 64 softmax rows (4t x 16 heads), one row per lane -> LDS [64][33].
// Phase 2: each thread owns 8 channels, slides once over the 34-row union
//          window, accumulating 4 outputs in regs (3.6x less L2 traffic).
// ---------------------------------------------------------------------------
__global__ __launch_bounds__(64) void dynconv_fused(const unsigned short* __restrict__ hb,
                                                    const unsigned short* __restrict__ lgb,
                                                    unsigned short* __restrict__ cvb) {
    __shared__ float w_s[64][33];

    // XCD chunked swizzle on (t-group major, b minor): adjacent t-groups
    // (overlapping h windows) land on the same XCD L2.
    const int bid = blockIdx.x;
    const int u   = (bid & 7) * 256 + (bid >> 3);   // 2048 % 8 == 0, bijective
    const int tg  = u >> 2;
    const int b   = u & 3;
    const int t0  = tg * 4;
    const int tid = threadIdx.x;

    // ---- Phase 1: softmax over K=31; lane = (dt, head) ----
    {
        const int dt = tid >> 4, hd = tid & 15;
        const unsigned short* lp = lgb + (size_t)((t0 + dt) * BB + b) * NPAD + hd * KK;
        float e[KK];
        float mx = -1e30f;
        #pragma unroll
        for (int k = 0; k < KK; ++k) { e[k] = bf2f(lp[k]); mx = fmaxf(mx, e[k]); }
        float sm = 0.f;
        #pragma unroll
        for (int k = 0; k < KK; ++k) { e[k] = __expf(e[k] - mx); sm += e[k]; }
        const float inv = 1.f / sm;
        #pragma unroll
        for (int k = 0; k < KK; ++k) w_s[tid][k] = e[k] * inv;
    }
    __syncthreads();

    // ---- Phase 2: rolling conv; thread = channel-group (8 ch) ----
    const int c0 = tid * 8;
    const int hd = tid >> 2;      // head = c0 >> 5
    float acc[4][8] = {};
    #pragma unroll
    for (int j = 0; j < 34; ++j) {             // tt = t0 - 15 + j
        const int tt = t0 - PP + j;
        if ((unsigned)tt >= TT) continue;
        const ushort8 hv = *(const ushort8*)&hb[(size_t)((tt * BB + b) * CC) + c0];
        float hf[8];
        #pragma unroll
        for (int cc = 0; cc < 8; ++cc) hf[cc] = bf2f(hv[cc]);
        #pragma unroll
        for (int dt = 0; dt < 4; ++dt) {
            const int k = j - dt;              // tap index for output t0+dt
            if (k < 0 || k >= KK) continue;
            const float wk = w_s[dt * 16 + hd][k];
            #pragma unroll
            for (int cc = 0; cc < 8; ++cc) acc[dt][cc] = fmaf(hf[cc], wk, acc[dt][cc]);
        }
    }
    #pragma unroll
    for (int dt = 0; dt < 4; ++dt) {
        ushort8 o;
        #pragma unroll
        for (int cc = 0; cc < 8; ++cc) o[cc] = f2bf(acc[dt][cc]);
        *(ushort8*)&cvb[(size_t)(((t0 + dt) * BB + b) * CC) + c0] = o;
    }
}

extern "C" void kernel_launch(void* const* d_in, const int* in_sizes, int n_in,
                              void* d_out, int out_size, void* d_ws, size_t ws_size,
                              hipStream_t stream) {
    const float* x  = (const float*)d_in[0];
    const float* W1 = (const float*)d_in[1];
    const float* b1 = (const float*)d_in[2];
    const float* Wl = (const float*)d_in[3];
    const float* W2 = (const float*)d_in[4];
    const float* b2 = (const float*)d_in[5];
    float* out = (float*)d_out;

    // workspace layout (all bf16 except out)
    unsigned short* xb  = (unsigned short*)d_ws;             // 8 MB
    unsigned short* hb  = xb  + (size_t)MM * CC;             // 8 MB
    unsigned short* cvb = hb  + (size_t)MM * CC;             // 8 MB
    unsigned short* W1b = cvb + (size_t)MM * CC;             // 0.5 MB
    unsigned short* Wlb = W1b + (size_t)CC * CC;             // 0.5 MB (padded)
    unsigned short* W2b = Wlb + (size_t)NPAD * CC;           // 0.5 MB
    unsigned short* lgb = W2b + (size_t)CC * CC;             // 8 MB bf16 logits

    const int nxc = MM * CC;           // 4194304

    cast_x<<<nxc / 1024, 256, 0, stream>>>(x, xb);
    cast_weights<<<768, 256, 0, stream>>>(W1, Wl, W2, W1b, Wlb, W2b);

    const int nblk = (MM / GBM) * (CC / GBN);   // 64 * 8 = 512

    // 1) h = x @ W1^T + b1   (bf16 out)
    gemm_nt_mfma<true><<<nblk, 256, 0, stream>>>(xb, W1b, b1, hb, CC, CC / GBN);
    // 2) logits = h @ Wl^T   (bf16 out, padded N)
    gemm_nt_mfma<true><<<nblk, 256, 0, stream>>>(hb, Wlb, nullptr, lgb, NPAD, NPAD / GBN);
    // 3+4) fused softmax + rolling dynamic conv (bf16 out)
    dynconv_fused<<<TT * BB / 4, 64, 0, stream>>>(hb, lgb, cvb);
    // 5) out = cv @ W2^T + b2  (fp32 out)
    gemm_nt_mfma<false><<<nblk, 256, 0, stream>>>(cvb, W2b, b2, out, CC, CC / GBN);
}

// Round 9
// 54.032 us; speedup vs baseline: 1.3277x; 1.3277x over previous
//
#include <hip/hip_runtime.h>
#include <hip/hip_bf16.h>

// Problem constants
#define TT 2048
#define BB 4
#define CC 512
#define HH 16
#define KK 31
#define PP 15
#define MM (TT*BB)      // 8192 rows
#define NPAD 512        // HK=496 padded to 512 (pad rows of Wl are zero)

typedef __bf16 bf16x8 __attribute__((ext_vector_type(8)));
typedef float f32x4 __attribute__((ext_vector_type(4)));
typedef unsigned short ushort8 __attribute__((ext_vector_type(8)));
typedef unsigned short ushort4v __attribute__((ext_vector_type(4)));

__device__ __forceinline__ float bf2f(unsigned short u) {
    return __uint_as_float(((unsigned int)u) << 16);
}
__device__ __forceinline__ unsigned short f2bf(float f) {
    unsigned int x = __float_as_uint(f);
    x += 0x7fffu + ((x >> 16) & 1u);
    return (unsigned short)(x >> 16);
}

// ---------------------------------------------------------------------------
// cast fp32 -> bf16 for x (4 elems/thread)
// ---------------------------------------------------------------------------
__global__ __launch_bounds__(256) void cast_x(const float* __restrict__ src,
                                              unsigned short* __restrict__ dst) {
    const int i = (blockIdx.x * 256 + threadIdx.x) * 4;
    const float4 v = *(const float4*)&src[i];
    ushort4v o = { f2bf(v.x), f2bf(v.y), f2bf(v.z), f2bf(v.w) };
    *(ushort4v*)&dst[i] = o;
}

// ---------------------------------------------------------------------------
// cast all three weight matrices in one dispatch (768 blocks x 1024 elems).
// Wl rows 496..511 are zero-padded.
// ---------------------------------------------------------------------------
__global__ __launch_bounds__(256) void cast_weights(const float* __restrict__ W1,
                                                    const float* __restrict__ Wl,
                                                    const float* __restrict__ W2,
                                                    unsigned short* __restrict__ W1b,
                                                    unsigned short* __restrict__ Wlb,
                                                    unsigned short* __restrict__ W2b) {
    const int b = blockIdx.x;
    const int i = (b & 255) * 1024 + threadIdx.x * 4;
    const float* src;
    unsigned short* dst;
    int n_src = 262144;
    if (b < 256)      { src = W1; dst = W1b; }
    else if (b < 512) { src = Wl; dst = Wlb; n_src = HH * KK * CC; }
    else              { src = W2; dst = W2b; }
    ushort4v o = {0, 0, 0, 0};
    if (i < n_src) {
        const float4 v = *(const float4*)&src[i];
        o[0] = f2bf(v.x); o[1] = f2bf(v.y); o[2] = f2bf(v.z); o[3] = f2bf(v.w);
    }
    *(ushort4v*)&dst[i] = o;
}

// ---------------------------------------------------------------------------
// bf16 MFMA GEMM-NT, 3-stage pipeline with counted vmcnt (R7 config, proven
// 55.7 us total): C[m,n] = sum_k A[m,k]*B[n,k] (+bias[n]); K=512 (NT=8xBK=64).
// 128x64 tile, 256 thr = 4 waves (2x2), each wave 64x32 out.
// Per iter t: {vmcnt(6); s_barrier; issue stage(t+2); ds_read+MFMA on buf t%3}.
// vmcnt never drains to 0 in-loop -> prefetch stays in flight across barriers.
// LDS 3*(16+8)=72 KB -> 2 blocks/CU. 512 blocks. Swizzle slot^=(row&7).
// ---------------------------------------------------------------------------
#define GBM 128
#define GBN 64
#define GBK 64
#define KC  512
#define NT  8

#define STAGE(kt, buf)                                                                         \
    do {                                                                                       \
        const int k0_ = (kt) * GBK;                                                            \
        _Pragma("unroll")                                                                      \
        for (int j = 0; j < 4; ++j)                                                            \
            __builtin_amdgcn_global_load_lds(                                                  \
                (const __attribute__((address_space(1))) void*)(gA[j] + k0_),                  \
                (__attribute__((address_space(3))) void*)(&As[buf][0] + j * 2048 + wv * 512),  \
                16, 0, 0);                                                                     \
        _Pragma("unroll")                                                                      \
        for (int j = 0; j < 2; ++j)                                                            \
            __builtin_amdgcn_global_load_lds(                                                  \
                (const __attribute__((address_space(1))) void*)(gB[j] + k0_),                  \
                (__attribute__((address_space(3))) void*)(&Bs[buf][0] + j * 2048 + wv * 512),  \
                16, 0, 0);                                                                     \
    } while (0)

template<bool OUT_BF16>
__global__ __launch_bounds__(256, 2) void gemm_nt_mfma(const unsigned short* __restrict__ A,
                                                       const unsigned short* __restrict__ B,
                                                       const float* __restrict__ bias,
                                                       void* __restrict__ Cout,
                                                       int N, int nn) {
    __shared__ short As[3][GBM * GBK];   // 3 x 16 KB
    __shared__ short Bs[3][GBN * GBK];   // 3 x 8 KB

    const int tid = threadIdx.x;
    const int l   = tid & 63;
    const int wv  = tid >> 6;      // wave 0..3
    const int wr  = wv >> 1;       // wave row (0..1) -> 64 rows
    const int wc  = wv & 1;        // wave col (0..1) -> 32 cols

    // chunked XCD swizzle; consecutive s share A panel in the XCD's L2
    const int s  = (blockIdx.x & 7) * (gridDim.x >> 3) + (blockIdx.x >> 3);
    const int bm = (s / nn) * GBM;
    const int bn = (s % nn) * GBN;

    // Staging: A tile 128 rows x 8 slots(16B) = 4 rounds x 256 thr; B tile
    // 64 x 8 = 2 rounds. Linear LDS dest; source slot pre-swizzled
    // slot' = slot ^ (row&7) (involution, matches swizzled ds_read).
    const unsigned short* gA[4];
    const unsigned short* gB[2];
    #pragma unroll
    for (int j = 0; j < 4; ++j) {
        const int idx16 = j * 256 + tid;
        const int r  = idx16 >> 3;
        const int sl = (idx16 & 7) ^ (r & 7);
        gA[j] = A + (size_t)(bm + r) * KC + sl * 8;
    }
    #pragma unroll
    for (int j = 0; j < 2; ++j) {
        const int idx16 = j * 256 + tid;
        const int r  = idx16 >> 3;
        const int sl = (idx16 & 7) ^ (r & 7);
        gB[j] = B + (size_t)(bn + r) * KC + sl * 8;
    }

    f32x4 acc[4][2] = {};

    const int lr = l & 15;     // fragment row-within-16
    const int ls = l >> 4;     // k-slot (8 bf16 each)
    int offA[4][2], offB[2][2];
    #pragma unroll
    for (int mi = 0; mi < 4; ++mi) {
        const int r = wr * 64 + mi * 16 + lr;
        #pragma unroll
        for (int ks = 0; ks < 2; ++ks)
            offA[mi][ks] = r * 64 + (((ks * 4 + ls) ^ (r & 7)) * 8);
    }
    #pragma unroll
    for (int ni = 0; ni < 2; ++ni) {
        const int r = wc * 32 + ni * 16 + lr;
        #pragma unroll
        for (int ks = 0; ks < 2; ++ks)
            offB[ni][ks] = r * 64 + (((ks * 4 + ls) ^ (r & 7)) * 8);
    }

    // prologue: stage tiles 0,1 (12 loads in flight per wave)
    STAGE(0, 0);
    STAGE(1, 1);

    #pragma unroll
    for (int kt = 0; kt < NT; ++kt) {
        // (a) wait: tile kt resident (keep later tiles in flight)
        if (kt < NT - 1) asm volatile("s_waitcnt vmcnt(6)" ::: "memory");
        else             asm volatile("s_waitcnt vmcnt(0)" ::: "memory");
        // (b) all waves: tile kt loaded everywhere, compute(kt-1) done everywhere
        __builtin_amdgcn_s_barrier();
        // (c) prefetch tile kt+2 (overwrites buf[(kt-1)%3], safe after barrier)
        if (kt + 2 < NT) STAGE(kt + 2, (kt + 2) % 3);

        // (d) compute on buf kt%3
        const int cb = kt % 3;
        bf16x8 af[4][2], bfv[2][2];
        #pragma unroll
        for (int mi = 0; mi < 4; ++mi)
            #pragma unroll
            for (int ks = 0; ks < 2; ++ks)
                af[mi][ks] = *(const bf16x8*)&As[cb][offA[mi][ks]];
        #pragma unroll
        for (int ni = 0; ni < 2; ++ni)
            #pragma unroll
            for (int ks = 0; ks < 2; ++ks)
                bfv[ni][ks] = *(const bf16x8*)&Bs[cb][offB[ni][ks]];

        #pragma unroll
        for (int mi = 0; mi < 4; ++mi)
            #pragma unroll
            for (int ni = 0; ni < 2; ++ni)
                #pragma unroll
                for (int ks = 0; ks < 2; ++ks)
                    acc[mi][ni] = __builtin_amdgcn_mfma_f32_16x16x32_bf16(af[mi][ks], bfv[ni][ks], acc[mi][ni], 0, 0, 0);
    }

    // C/D layout (m89): col = lane&15, row = (lane>>4)*4 + j
    #pragma unroll
    for (int mi = 0; mi < 4; ++mi) {
        const int row0 = bm + wr * 64 + mi * 16 + ls * 4;
        #pragma unroll
        for (int ni = 0; ni < 2; ++ni) {
            const int col = bn + wc * 32 + ni * 16 + lr;
            const float bv = bias ? bias[col] : 0.0f;
            #pragma unroll
            for (int j = 0; j < 4; ++j) {
                const float v = acc[mi][ni][j] + bv;
                if (OUT_BF16)
                    ((unsigned short*)Cout)[(size_t)(row0 + j) * N + col] = f2bf(v);
                else
                    ((float*)Cout)[(size_t)(row0 + j) * N + col] = v;
            }
        }
    }
}

// ---------------------------------------------------------------------------
// Fused softmax + rolling dynamic conv (R8 version — kept).
// Block = (4 consecutive t, one b), 64 threads (1 wave).
// Phase 1: 64 softmax rows (4t x 16 heads), one row per lane -> LDS [64][33].
// Phase 2: each thread owns 8 channels, slides once over the 34-row union
//          window, accumulating 4 outputs in regs (3.6x less L2 traffic).
// ---------------------------------------------------------------------------
__global__ __launch_bounds__(64) void dynconv_fused(const unsigned short* __restrict__ hb,
                                                    const unsigned short* __restrict__ lgb,
                                                    unsigned short* __restrict__ cvb) {
    __shared__ float w_s[64][33];

    const int bid = blockIdx.x;
    const int u   = (bid & 7) * 256 + (bid >> 3);   // 2048 % 8 == 0, bijective
    const int tg  = u >> 2;
    const int b   = u & 3;
    const int t0  = tg * 4;
    const int tid = threadIdx.x;

    // ---- Phase 1: softmax over K=31; lane = (dt, head) ----
    {
        const int dt = tid >> 4, hd = tid & 15;
        const unsigned short* lp = lgb + (size_t)((t0 + dt) * BB + b) * NPAD + hd * KK;
        float e[KK];
        float mx = -1e30f;
        #pragma unroll
        for (int k = 0; k < KK; ++k) { e[k] = bf2f(lp[k]); mx = fmaxf(mx, e[k]); }
        float sm = 0.f;
        #pragma unroll
        for (int k = 0; k < KK; ++k) { e[k] = __expf(e[k] - mx); sm += e[k]; }
        const float inv = 1.f / sm;
        #pragma unroll
        for (int k = 0; k < KK; ++k) w_s[tid][k] = e[k] * inv;
    }
    __syncthreads();

    // ---- Phase 2: rolling conv; thread = channel-group (8 ch) ----
    const int c0 = tid * 8;
    const int hd = tid >> 2;      // head = c0 >> 5
    float acc[4][8] = {};
    #pragma unroll
    for (int j = 0; j < 34; ++j) {             // tt = t0 - 15 + j
        const int tt = t0 - PP + j;
        if ((unsigned)tt >= TT) continue;
        const ushort8 hv = *(const ushort8*)&hb[(size_t)((tt * BB + b) * CC) + c0];
        float hf[8];
        #pragma unroll
        for (int cc = 0; cc < 8; ++cc) hf[cc] = bf2f(hv[cc]);
        #pragma unroll
        for (int dt = 0; dt < 4; ++dt) {
            const int k = j - dt;              // tap index for output t0+dt
            if (k < 0 || k >= KK) continue;
            const float wk = w_s[dt * 16 + hd][k];
            #pragma unroll
            for (int cc = 0; cc < 8; ++cc) acc[dt][cc] = fmaf(hf[cc], wk, acc[dt][cc]);
        }
    }
    #pragma unroll
    for (int dt = 0; dt < 4; ++dt) {
        ushort8 o;
        #pragma unroll
        for (int cc = 0; cc < 8; ++cc) o[cc] = f2bf(acc[dt][cc]);
        *(ushort8*)&cvb[(size_t)(((t0 + dt) * BB + b) * CC) + c0] = o;
    }
}

extern "C" void kernel_launch(void* const* d_in, const int* in_sizes, int n_in,
                              void* d_out, int out_size, void* d_ws, size_t ws_size,
                              hipStream_t stream) {
    const float* x  = (const float*)d_in[0];
    const float* W1 = (const float*)d_in[1];
    const float* b1 = (const float*)d_in[2];
    const float* Wl = (const float*)d_in[3];
    const float* W2 = (const float*)d_in[4];
    const float* b2 = (const float*)d_in[5];
    float* out = (float*)d_out;

    // workspace layout (all bf16 except out)
    unsigned short* xb  = (unsigned short*)d_ws;             // 8 MB
    unsigned short* hb  = xb  + (size_t)MM * CC;             // 8 MB
    unsigned short* cvb = hb  + (size_t)MM * CC;             // 8 MB
    unsigned short* W1b = cvb + (size_t)MM * CC;             // 0.5 MB
    unsigned short* Wlb = W1b + (size_t)CC * CC;             // 0.5 MB (padded)
    unsigned short* W2b = Wlb + (size_t)NPAD * CC;           // 0.5 MB
    unsigned short* lgb = W2b + (size_t)CC * CC;             // 8 MB bf16 logits

    const int nxc = MM * CC;           // 4194304

    cast_x<<<nxc / 1024, 256, 0, stream>>>(x, xb);
    cast_weights<<<768, 256, 0, stream>>>(W1, Wl, W2, W1b, Wlb, W2b);

    const int nblk = (MM / GBM) * (CC / GBN);   // 64 * 8 = 512

    // 1) h = x @ W1^T + b1   (bf16 out)
    gemm_nt_mfma<true><<<nblk, 256, 0, stream>>>(xb, W1b, b1, hb, CC, CC / GBN);
    // 2) logits = h @ Wl^T   (bf16 out, padded N)
    gemm_nt_mfma<true><<<nblk, 256, 0, stream>>>(hb, Wlb, nullptr, lgb, NPAD, NPAD / GBN);
    // 3+4) fused softmax + rolling dynamic conv (bf16 out)
    dynconv_fused<<<TT * BB / 4, 64, 0, stream>>>(hb, lgb, cvb);
    // 5) out = cv @ W2^T + b2  (fp32 out)
    gemm_nt_mfma<false><<<nblk, 256, 0, stream>>>(cvb, W2b, b2, out, CC, CC / GBN);
}